// Round 2
// baseline (448.991 us; speedup 1.0000x reference)
//
#include <hip/hip_runtime.h>

#define NC   16      // channels
#define NP   48      // perception channels = 3*NC
#define NH   128     // hidden
#define HDIM 256
#define WDIM 256
#define HW   (HDIM*WDIM)

#define PSTR  48     // sP row stride (bf16): exactly NP, no pad (q>=2 t=1 reg-zeroed)
#define HSTR  136    // H row stride (bf16)
#define W2STR 136    // w2 scratch row stride (bf16)

typedef __attribute__((ext_vector_type(8))) short short8;  // 8 bf16 = 1 MFMA operand
typedef __attribute__((ext_vector_type(4))) float f32x4;   // MFMA accumulator
typedef __attribute__((ext_vector_type(4))) int   int4v;   // 16B LDS store

// packed f32x2 -> bf16x2 (RNE), one VOP3 instead of ~9 VALU for a manual pair
__device__ __forceinline__ unsigned cvt_pk(float lo, float hi) {
    unsigned r;
    asm("v_cvt_pk_bf16_f32 %0, %1, %2" : "=v"(r) : "v"(lo), "v"(hi));
    return r;
}

__global__ __launch_bounds__(256, 4) void nca_mfma_kernel(
    const float* __restrict__ grid,
    const float* __restrict__ noise,
    const float* __restrict__ w1,
    const float* __restrict__ b1,
    const float* __restrict__ w2,
    const float* __restrict__ b2,
    float* __restrict__ out)
{
    // w1 in MFMA-B-fragment layout, LIVE through phase 4 (no 64-VGPR w1f array):
    // [n][ t=0: 512 shorts (64 lanes x 8) | t=1: 256 shorts (lanes 0..31 x 8) ]
    __shared__ short sW1F[8 * 768];          // 12288 B
    // perception rows [256][PSTR]; doubles as: w2 scratch (phase 0, bytes 0..4352),
    // channel-staging buffer (phase 1, bytes 21472..24568), H overlay (phase 4,
    // per-wave rows 16.. of its own 64-row span). Total LDS = 36864 B -> 4 blocks/CU.
    __shared__ short sP[HDIM * PSTR];        // 24576 B

    short* w2s = sP;                          // phase-0 scratch
    float* sS  = (float*)&sP[10736];          // 3 rows x 258 floats = 3096 B (sP tail)

    const int tid  = threadIdx.x;
    const int b    = blockIdx.x >> 8;
    const int y    = blockIdx.x & 255;
    const int wv   = tid >> 6;
    const int lane = tid & 63;
    const int q    = lane >> 4;
    const int l15  = lane & 15;

    // ---------- Phase 0: stage weights ----------
    {
        // w1 -> fragment layout. thread t: row o=t>>1, k-range 24*(t&1)..+23 (3 groups of 8)
        const int o = tid >> 1, half = tid & 1;
        const float* src = w1 + o * NP + 24 * half;
        const int n = o >> 4, r15 = o & 15;
        #pragma unroll
        for (int g = 0; g < 3; ++g) {
            const int k0 = 24 * half + 8 * g;
            const int tt = k0 >> 5, qq = (k0 & 31) >> 3;
            unsigned u0 = cvt_pk(src[8*g+0], src[8*g+1]);
            unsigned u1 = cvt_pk(src[8*g+2], src[8*g+3]);
            unsigned u2 = cvt_pk(src[8*g+4], src[8*g+5]);
            unsigned u3 = cvt_pk(src[8*g+6], src[8*g+7]);
            int4v v = {(int)u0, (int)u1, (int)u2, (int)u3};
            *(int4v*)&sW1F[n*768 + (tt ? 512 : 0) + (qq*16 + r15)*8] = v;
        }
        // w2 raw rows -> bf16 scratch
        const int j = tid >> 4, seg = tid & 15;
        const float* s2 = w2 + j * NH + seg * 8;
        unsigned v0 = cvt_pk(s2[0], s2[1]), v1 = cvt_pk(s2[2], s2[3]);
        unsigned v2 = cvt_pk(s2[4], s2[5]), v3 = cvt_pk(s2[6], s2[7]);
        int4v vv = {(int)v0, (int)v1, (int)v2, (int)v3};
        *(int4v*)&w2s[j * W2STR + seg * 8] = vv;
        // staging halo zero cells (col 256 of each row); never overwritten in phase 1
        if (tid < 3) { sS[tid*258 + 256] = 0.f; sS[tid*258 + 257] = 0.f; }
    }
    __syncthreads();

    // w2 frags in PERMUTED o-space (o' = a*8 + j' <-> o = j'*16 + a, a = 4t+q);
    // H is written with the same permutation, so the contraction is unchanged.
    short8 w2f[4];
    #pragma unroll
    for (int t = 0; t < 4; ++t) {
        short8 v;
        #pragma unroll
        for (int jj = 0; jj < 8; ++jj) v[jj] = w2s[l15 * W2STR + jj*16 + 4*t + q];
        w2f[t] = v;
    }
    float b1v[8];
    #pragma unroll
    for (int n = 0; n < 8; ++n) b1v[n] = b1[16*n + l15];
    const float b2v = b2[l15];

    // ---------- Phase 1: stencil with per-channel LDS row staging ----------
    // waves 0..2 each stage one halo row (T/M/B) as float4; all threads stencil.
    const int  x   = tid;
    const bool ld  = (tid < 192);
    const int  r   = tid >> 6, seg = tid & 63;
    int rowY = y - 1 + r; rowY = rowY < 0 ? 0 : (rowY > 255 ? 255 : rowY);
    const bool zr = (r == 0 && y == 0) || (r == 2 && y == 255);  // wave-uniform
    const float* gp = grid + (size_t)b * NC * HW + (size_t)rowY * WDIM + 4 * seg;

    float4 v0 = {0.f, 0.f, 0.f, 0.f};
    if (ld) { v0 = *(const float4*)gp; gp += HW; if (zr) { float4 z = {0,0,0,0}; v0 = z; } }
    // note: sS writes are disjoint from w2s scratch (bytes 21472+ vs 0..4352)
    if (ld) *(float4*)&sS[r*258 + 4*seg] = v0;
    __syncthreads();                      // channel 0 staged

    const int xl = x ? (x - 1) : 256;     // halo cell (stored zero)
    const int xr = (x < 255) ? (x + 1) : 256;

    unsigned pk[24];
    float carry = 0.f;
    #pragma unroll
    for (int c = 0; c < 16; ++c) {
        float4 vn = {0.f, 0.f, 0.f, 0.f};
        if (ld && c < 15) { vn = *(const float4*)gp; gp += HW; if (zr) { float4 z = {0,0,0,0}; vn = z; } }

        const float tl = sS[xl],       tm = sS[x],       tr = sS[xr];
        const float ml = sS[258 + xl], mm = sS[258 + x], mr = sS[258 + xr];
        const float bl = sS[516 + xl], bm = sS[516 + x], br = sS[516 + xr];
        const float p1 = (tl + tr + 2.f*ml - 2.f*mr + bl - br) * 0.125f;
        const float p2 = (tl + 2.f*tm + tr - bl - 2.f*bm - br) * 0.125f;
        if (c & 1) { pk[(3*c - 1) / 2] = cvt_pk(carry, mm); pk[(3*c + 1) / 2] = cvt_pk(p1, p2); }
        else       { pk[3*c / 2]       = cvt_pk(mm, p1);    carry = p2; }

        __syncthreads();                  // all stencil reads of channel c done
        if (ld && c < 15) *(float4*)&sS[r*258 + 4*seg] = vn;
        __syncthreads();                  // channel c+1 staged
    }

    // flush pk -> sP row x (staging area + w2 scratch are dead; barriers above protect)
    {
        short* row = &sP[x * PSTR];
        #pragma unroll
        for (int i = 0; i < 6; ++i) {
            int4v v = {(int)pk[4*i], (int)pk[4*i+1], (int)pk[4*i+2], (int)pk[4*i+3]};
            *(int4v*)&row[8*i] = v;
        }
    }
    __syncthreads();   // defensive: sP fully built before phase 4 reads

    // ---------- Phase 4: MFMA MLP over this wave's 4 pixel-tiles ----------
    // prefetch A-frags for mt=1..3 (their sP rows get overlaid by H below)
    short8 aF0[3], aF1[3];
    #pragma unroll
    for (int m = 1; m < 4; ++m) {
        const short* pr = &sP[((wv*4 + m)*16 + l15) * PSTR];
        aF0[m-1] = *(const short8*)&pr[8*q];
        short8 a1 = {};
        if (q < 2) a1 = *(const short8*)&pr[32 + 8*q];   // k=32..47 real; q>=2 -> zero
        aF1[m-1] = a1;
    }
    // H overlays own-wave sP rows 16.. (4352 B needed, 4608 B available; 16B-aligned)
    short* Hb = &sP[(wv*64 + 16) * PSTR];

    #pragma unroll
    for (int mt = 0; mt < 4; ++mt) {
        short8 a0, a1;
        if (mt == 0) {       // rows 0..15 of own span are never overlaid: read JIT
            const short* pr = &sP[(wv*64 + l15) * PSTR];
            a0 = *(const short8*)&pr[8*q];
            short8 z = {}; a1 = z;
            if (q < 2) a1 = *(const short8*)&pr[32 + 8*q];
        } else { a0 = aF0[mt-1]; a1 = aF1[mt-1]; }

        f32x4 acc[8];
        #pragma unroll
        for (int n = 0; n < 8; ++n) { f32x4 t4 = {b1v[n], b1v[n], b1v[n], b1v[n]}; acc[n] = t4; }
        #pragma unroll
        for (int n = 0; n < 8; ++n) {      // k = 0..31
            const short8 bf0 = *(const short8*)&sW1F[n*768 + lane*8];
            acc[n] = __builtin_amdgcn_mfma_f32_16x16x32_bf16(a0, bf0, acc[n], 0, 0, 0);
        }
        #pragma unroll
        for (int n = 0; n < 8; ++n) {      // k = 32..63 (real data only in lanes 0..31)
            short8 bf1 = {};
            if (lane < 32) bf1 = *(const short8*)&sW1F[n*768 + 512 + lane*8];
            acc[n] = __builtin_amdgcn_mfma_f32_16x16x32_bf16(a1, bf1, acc[n], 0, 0, 0);
        }

        // relu -> bf16 -> H' [m=q*4+r][o'=l15*8+n] (one b128 per r)
        #pragma unroll
        for (int rr = 0; rr < 4; ++rr) {
            unsigned h0 = cvt_pk(fmaxf(acc[0][rr], 0.f), fmaxf(acc[1][rr], 0.f));
            unsigned h1 = cvt_pk(fmaxf(acc[2][rr], 0.f), fmaxf(acc[3][rr], 0.f));
            unsigned h2 = cvt_pk(fmaxf(acc[4][rr], 0.f), fmaxf(acc[5][rr], 0.f));
            unsigned h3 = cvt_pk(fmaxf(acc[6][rr], 0.f), fmaxf(acc[7][rr], 0.f));
            int4v v = {(int)h0, (int)h1, (int)h2, (int)h3};
            *(int4v*)&Hb[(q*4 + rr) * HSTR + l15 * 8] = v;
        }
        // GEMM2: A[m=l15][k=o'=32t+8q+j] from H', B = w2f (same permutation)
        f32x4 acc2 = {b2v, b2v, b2v, b2v};
        #pragma unroll
        for (int t = 0; t < 4; ++t) {
            const short8 af = *(const short8*)&Hb[l15 * HSTR + 32*t + 8*q];
            acc2 = __builtin_amdgcn_mfma_f32_16x16x32_bf16(af, w2f[t], acc2, 0, 0, 0);
        }
        // Epilogue straight from C-layout: lane = (channel j=l15, pixels px0+4q..+3)
        const int px0 = (wv*4 + mt) * 16;
        const int px  = px0 + 4*q;
        const size_t gi = (size_t)b * NC * HW + (size_t)l15 * HW + (size_t)y * WDIM + px;
        const float4 g  = *(const float4*)&grid[gi];
        const float4 nz = *(const float4*)&noise[(size_t)b * HW + (size_t)y * WDIM + px];
        float4 o;
        o.x = fminf(fmaxf(g.x + acc2[0] * (nz.x < 0.5f ? 1.f : 0.f), -2.f), 2.f);
        o.y = fminf(fmaxf(g.y + acc2[1] * (nz.y < 0.5f ? 1.f : 0.f), -2.f), 2.f);
        o.z = fminf(fmaxf(g.z + acc2[2] * (nz.z < 0.5f ? 1.f : 0.f), -2.f), 2.f);
        o.w = fminf(fmaxf(g.w + acc2[3] * (nz.w < 0.5f ? 1.f : 0.f), -2.f), 2.f);
        *(float4*)&out[gi] = o;
    }
}

extern "C" void kernel_launch(void* const* d_in, const int* in_sizes, int n_in,
                              void* d_out, int out_size, void* d_ws, size_t ws_size,
                              hipStream_t stream) {
    const float* grid  = (const float*)d_in[0];
    const float* noise = (const float*)d_in[1];
    const float* w1    = (const float*)d_in[2];
    const float* b1    = (const float*)d_in[3];
    const float* w2    = (const float*)d_in[4];
    const float* b2    = (const float*)d_in[5];
    float* out = (float*)d_out;

    dim3 g(32 * 256);   // one block per (batch, row)
    nca_mfma_kernel<<<g, 256, 0, stream>>>(grid, noise, w1, b1, w2, b2, out);
}